// Round 2
// baseline (13509.752 us; speedup 1.0000x reference)
//
#include <hip/hip_runtime.h>
#include <hip/hip_bf16.h>
#include <math.h>

// Problem constants
#define BB 4
#define TT 1536
#define CC 1536
#define HH 8
#define DKk 64
#define DVv 192
#define NBASIS 32
#define LREL 3071          // 2T-1
#define MROWS 6144         // B*T

// ---------------------------------------------------------------------------
// Stage 0: dtype detection. If d_in really holds bf16, even-indexed bf16
// elements of x are ~N(0,1). If it holds fp32 read as bf16, even-indexed
// elements are the LOW 16 bits of floats -> random exponents (~10% in range).
// ---------------------------------------------------------------------------
__global__ void detect_kernel(const void* __restrict__ x, int* __restrict__ flag) {
  if (threadIdx.x == 0 && blockIdx.x == 0) {
    const __hip_bfloat16* h = (const __hip_bfloat16*)x;
    int cnt = 0;
    for (int i = 0; i < 64; ++i) {
      float v = fabsf((float)h[2 * i]);
      if (v > 1e-5f && v < 256.0f) cnt++;   // NaN compares false -> not counted
    }
    *flag = (cnt >= 32) ? 1 : 0;  // 1 => inputs are bf16
  }
}

// Convert any input (bf16 or fp32 per flag) to canonical fp32.
__global__ __launch_bounds__(256) void convert_kernel(const void* __restrict__ src,
                                                      float* __restrict__ dst, int n,
                                                      const int* __restrict__ flag) {
  const int i = blockIdx.x * 256 + threadIdx.x;
  if (i >= n) return;
  if (*flag) dst[i] = (float)((const __hip_bfloat16*)src)[i];
  else       dst[i] = ((const float*)src)[i];
}

// ---------------------------------------------------------------------------
// Stage 1: gamma-basis max over pos (fp64). One block per basis j.
// ---------------------------------------------------------------------------
__global__ void gmax_kernel(double* __restrict__ gmax) {
  const int j = blockIdx.x;
  const double mean = 48.0 + 1488.0 * (double)j / 31.0;   // linspace(48,1536,32)
  const double conc = (mean / 24.0) * (mean / 24.0);
  const double rate = mean / 576.0;
  const double log_norm = lgamma(conc) - conc * log(rate);
  double mx = 1e-8;  // pos==0 contributes exactly 1e-8
  for (int pos = 1 + threadIdx.x; pos <= 1535; pos += 256) {
    double p = exp((conc - 1.0) * log((double)pos) - rate * (double)pos - log_norm) + 1e-8;
    mx = fmax(mx, p);
  }
  __shared__ double red[256];
  red[threadIdx.x] = mx;
  __syncthreads();
  for (int s = 128; s > 0; s >>= 1) {
    if (threadIdx.x < s) red[threadIdx.x] = fmax(red[threadIdx.x], red[threadIdx.x + s]);
    __syncthreads();
  }
  if (threadIdx.x == 0) gmax[j] = red[0];
}

// ---------------------------------------------------------------------------
// Stage 2: pe[l, f] for l in [0,3071), f in [0,192). fp64 math, fp32 store.
// ---------------------------------------------------------------------------
__global__ void pe_kernel(float* __restrict__ pe, const double* __restrict__ gmax) {
  const int l = blockIdx.x;
  const int f = threadIdx.x;  // 0..191
  const int dist = l - (TT - 1);
  const int pos = dist < 0 ? -dist : dist;
  const int base = f % 96;
  const int cls = base / 32;
  const int j = base % 32;
  double v;
  if (cls == 0) {
    const double max_range = log(1536.0) / log(2.0);
    const double e = 3.0 + (max_range - 3.0) * (double)j / 31.0;
    const double hl = exp2(e);
    v = exp2(-(double)pos / hl);
  } else if (cls == 1) {
    const double width = exp2((double)(j + 1)) - 1.0;
    v = (width > (double)pos) ? 1.0 : 0.0;
  } else {
    const double mean = 48.0 + 1488.0 * (double)j / 31.0;
    const double conc = (mean / 24.0) * (mean / 24.0);
    const double rate = mean / 576.0;
    double p;
    if (pos == 0) {
      p = 1e-8;
    } else {
      const double log_norm = lgamma(conc) - conc * log(rate);
      p = exp((conc - 1.0) * log((double)pos) - rate * (double)pos - log_norm) + 1e-8;
    }
    v = p / gmax[j];
  }
  float out = (float)v;
  if (f >= 96) {
    float sgn = (dist > 0) ? 1.f : (dist < 0 ? -1.f : 0.f);
    out *= sgn;
  }
  pe[(size_t)l * 192 + f] = out;
}

// ---------------------------------------------------------------------------
// Stage 3: rKt[h*64+d][l] = sum_f pe[l,f] * W_rel_k[f, h*64+d]   (transposed)
// ---------------------------------------------------------------------------
__global__ __launch_bounds__(512) void relk_kernel(const float* __restrict__ pe,
                                                   const float* __restrict__ Wrk,
                                                   float* __restrict__ rKt) {
  __shared__ float pes[8][192];
  const int l0 = blockIdx.x * 8;
  const int nrows = (LREL - l0) < 8 ? (LREL - l0) : 8;
  const int tid = threadIdx.x;
  for (int idx = tid; idx < nrows * 192; idx += 512) {
    int r = idx / 192, f = idx % 192;
    pes[r][f] = pe[(size_t)(l0 + r) * 192 + f];
  }
  __syncthreads();
  float acc[8] = {0.f, 0.f, 0.f, 0.f, 0.f, 0.f, 0.f, 0.f};
  for (int f = 0; f < 192; ++f) {
    float w = Wrk[(size_t)f * 512 + tid];
#pragma unroll
    for (int r = 0; r < 8; ++r) acc[r] += pes[r][f] * w;
  }
  for (int r = 0; r < nrows; ++r)
    rKt[(size_t)tid * LREL + (l0 + r)] = acc[r];
}

// ---------------------------------------------------------------------------
// Tiled fp32 GEMM: C[M,N] = A[M,K] @ B[K,N]. 64x64 tile, BK=16, 256 thr, 4x4.
// Epilogue: optional bias add; store fp32 to C, or (flag) bf16/fp32 to d_out.
// ---------------------------------------------------------------------------
template <bool TO_OUT, bool BIAS>
__global__ __launch_bounds__(256) void gemm64(const float* __restrict__ A,
                                              const float* __restrict__ B,
                                              void* __restrict__ Cout,
                                              const float* __restrict__ bias,
                                              int M, int N, int K,
                                              const int* __restrict__ flag) {
  __shared__ float As[64][17];
  __shared__ float Bs[16][68];
  const int tid = threadIdx.x;
  const int tx = tid & 15, ty = tid >> 4;
  const int row0 = blockIdx.y * 64, col0 = blockIdx.x * 64;
  float acc[4][4] = {};
  for (int k0 = 0; k0 < K; k0 += 16) {
    {
      const int ar = tid >> 2, ac = (tid & 3) * 4;
      const float* ap = A + (size_t)(row0 + ar) * K + (k0 + ac);
#pragma unroll
      for (int i = 0; i < 4; ++i) As[ar][ac + i] = ap[i];
      const int bc = tid & 63, br4 = (tid >> 6) * 4;
#pragma unroll
      for (int i = 0; i < 4; ++i)
        Bs[br4 + i][bc] = B[(size_t)(k0 + br4 + i) * N + (col0 + bc)];
    }
    __syncthreads();
#pragma unroll
    for (int kk = 0; kk < 16; ++kk) {
      float a[4], b[4];
#pragma unroll
      for (int i = 0; i < 4; ++i) a[i] = As[ty * 4 + i][kk];
#pragma unroll
      for (int j = 0; j < 4; ++j) b[j] = Bs[kk][tx * 4 + j];
#pragma unroll
      for (int i = 0; i < 4; ++i)
#pragma unroll
        for (int j = 0; j < 4; ++j) acc[i][j] += a[i] * b[j];
    }
    __syncthreads();
  }
  const bool obf = TO_OUT ? (*flag != 0) : false;
#pragma unroll
  for (int i = 0; i < 4; ++i) {
    const int r = row0 + ty * 4 + i;
#pragma unroll
    for (int j = 0; j < 4; ++j) {
      const int c = col0 + tx * 4 + j;
      float v = acc[i][j];
      if (BIAS) v += bias[c];
      if (TO_OUT) {
        if (obf) ((__hip_bfloat16*)Cout)[(size_t)r * N + c] = __float2bfloat16(v);
        else     ((float*)Cout)[(size_t)r * N + c] = v;
      } else {
        ((float*)Cout)[(size_t)r * N + c] = v;
      }
    }
  }
}

// ---------------------------------------------------------------------------
// Stage 5: K^T scatter: Kt[b,h,d,k] from tmpK[b*T+k, h*64+d]
// ---------------------------------------------------------------------------
__global__ __launch_bounds__(256) void scatter_k(const float* __restrict__ tmpK,
                                                 float* __restrict__ Kt) {
  const size_t idx = (size_t)blockIdx.x * 256 + threadIdx.x;  // over 6144*512
  const int n = (int)(idx & 511);
  const int m = (int)(idx >> 9);
  const int b = m / TT, t = m % TT;
  const int h = n >> 6, d = n & 63;
  Kt[((size_t)(b * HH + h) * 64 + d) * TT + t] = tmpK[idx];
}

// ---------------------------------------------------------------------------
// Stage 6: flash attention, one wave per query row.
// logits[k] = (Q*s + rwb) . K[k]  +  (Q*s + rrb) . rK[k - q + T-1]
// ---------------------------------------------------------------------------
__device__ inline float wave_max(float v) {
#pragma unroll
  for (int o = 32; o > 0; o >>= 1) v = fmaxf(v, __shfl_xor(v, o));
  return v;
}
__device__ inline float wave_sum(float v) {
#pragma unroll
  for (int o = 32; o > 0; o >>= 1) v += __shfl_xor(v, o);
  return v;
}

__global__ __launch_bounds__(256) void attn_kernel(const float* __restrict__ tmpQ,
                                                   const float* __restrict__ rwb,
                                                   const float* __restrict__ rrb,
                                                   const float* __restrict__ Kt,
                                                   const float* __restrict__ rKt,
                                                   const float* __restrict__ V,
                                                   float* __restrict__ O) {
  const int wid = threadIdx.x >> 6;
  const int lane = threadIdx.x & 63;
  const int row = blockIdx.x * 4 + wid;  // [0, B*H*T)
  const int b = row / (HH * TT);
  const int h = (row / TT) & (HH - 1);
  const int q = row % TT;

  const float qv = tmpQ[((size_t)(b * TT + q)) * 512 + h * 64 + lane] * 0.125f;
  const float qw = qv + rwb[h * 64 + lane];
  const float qr = qv + rrb[h * 64 + lane];
  const float* __restrict__ Ktbh = Kt + ((size_t)(b * HH + h) * 64) * TT;
  const float* __restrict__ rKth = rKt + ((size_t)h * 64) * LREL;
  const float* __restrict__ Vb = V + (size_t)b * TT * 1536 + h * DVv;

  float acc0 = 0.f, acc1 = 0.f, acc2 = 0.f;
  float m = -INFINITY, lsum = 0.f;

  for (int kt = 0; kt < TT; kt += 64) {
    const int k = kt + lane;
    const int lidx = k - q + (TT - 1);  // in [0, 3071)
    float s = 0.f;
#pragma unroll
    for (int d = 0; d < 64; ++d) {
      const float bw = __shfl(qw, d);
      const float br = __shfl(qr, d);
      s += bw * Ktbh[(size_t)d * TT + k];
      s += br * rKth[(size_t)d * LREL + lidx];
    }
    const float ms = wave_max(s);
    const float newm = fmaxf(m, ms);
    const float alpha = __expf(m - newm);  // first tile: exp(-inf)=0
    const float p = __expf(s - newm);
    const float ps = wave_sum(p);
    lsum = lsum * alpha + ps;
    acc0 *= alpha;
    acc1 *= alpha;
    acc2 *= alpha;
    const float* __restrict__ vrow = Vb + (size_t)kt * 1536;
#pragma unroll
    for (int jj = 0; jj < 64; ++jj) {
      const float pj = __shfl(p, jj);
      const float* vr = vrow + (size_t)jj * 1536;
      acc0 += pj * vr[lane];
      acc1 += pj * vr[lane + 64];
      acc2 += pj * vr[lane + 128];
    }
    m = newm;
  }
  const float inv = 1.f / lsum;
  float* op = O + ((size_t)(b * TT + q)) * 1536 + h * DVv;
  op[lane] = acc0 * inv;
  op[lane + 64] = acc1 * inv;
  op[lane + 128] = acc2 * inv;
}

// ---------------------------------------------------------------------------
extern "C" void kernel_launch(void* const* d_in, const int* in_sizes, int n_in,
                              void* d_out, int out_size, void* d_ws, size_t ws_size,
                              hipStream_t stream) {
  const void* x     = d_in[0];
  const void* W_q   = d_in[1];
  const void* W_k   = d_in[2];
  const void* W_v   = d_in[3];
  const void* W_rel = d_in[4];
  const void* W_out = d_in[5];
  const void* b_out = d_in[6];
  const void* r_w_b = d_in[7];
  const void* r_r_b = d_in[8];

  float* ws = (float*)d_ws;
  int*    flag = (int*)d_ws;                 // 16 floats reserved
  double* gmax = (double*)(ws + 16);         // 32 doubles = 64 floats
  float* pe    = ws + 16 + 64;
  float* rKt   = pe   + (size_t)LREL * 192;       // 512*3071
  float* xF    = rKt  + (size_t)512 * LREL;       // 6144*1536
  float* WqF   = xF   + (size_t)MROWS * 1536;     // 1536*512
  float* WkF   = WqF  + (size_t)1536 * 512;
  float* WvF   = WkF  + (size_t)1536 * 512;       // 1536*1536
  float* WrelF = WvF  + (size_t)1536 * 1536;      // 192*512
  float* WoutF = WrelF + (size_t)192 * 512;       // 1536*1536
  float* boutF = WoutF + (size_t)1536 * 1536;     // 1536
  float* rwbF  = boutF + 1536;                    // 512
  float* rrbF  = rwbF + 512;                      // 512
  float* tmpQ  = rrbF + 512;                      // 6144*512
  float* tmpK  = tmpQ + (size_t)MROWS * 512;
  float* V     = tmpK + (size_t)MROWS * 512;      // 6144*1536
  float* Kt    = V    + (size_t)MROWS * 1536;     // 6144*512
  float* O     = Kt   + (size_t)MROWS * 512;      // 6144*1536
  float* endp  = O    + (size_t)MROWS * 1536;
  if (ws_size < (size_t)(endp - ws) * sizeof(float)) return;  // ws too small

  detect_kernel<<<1, 64, 0, stream>>>(x, flag);

  auto conv = [&](const void* src, float* dst, int n) {
    convert_kernel<<<(n + 255) / 256, 256, 0, stream>>>(src, dst, n, flag);
  };
  conv(x,     xF,    MROWS * 1536);
  conv(W_q,   WqF,   1536 * 512);
  conv(W_k,   WkF,   1536 * 512);
  conv(W_v,   WvF,   1536 * 1536);
  conv(W_rel, WrelF, 192 * 512);
  conv(W_out, WoutF, 1536 * 1536);
  conv(b_out, boutF, 1536);
  conv(r_w_b, rwbF,  512);
  conv(r_r_b, rrbF,  512);

  gmax_kernel<<<32, 256, 0, stream>>>(gmax);
  pe_kernel<<<LREL, 192, 0, stream>>>(pe, gmax);
  relk_kernel<<<(LREL + 7) / 8, 512, 0, stream>>>(pe, WrelF, rKt);

  gemm64<false, false><<<dim3(8, 96), 256, 0, stream>>>(
      xF, WqF, tmpQ, nullptr, MROWS, 512, CC, flag);
  gemm64<false, false><<<dim3(8, 96), 256, 0, stream>>>(
      xF, WkF, tmpK, nullptr, MROWS, 512, CC, flag);
  gemm64<false, false><<<dim3(24, 96), 256, 0, stream>>>(
      xF, WvF, V, nullptr, MROWS, 1536, CC, flag);

  scatter_k<<<12288, 256, 0, stream>>>(tmpK, Kt);

  attn_kernel<<<12288, 256, 0, stream>>>(tmpQ, rwbF, rrbF, Kt, rKt, V, O);

  gemm64<true, true><<<dim3(24, 96), 256, 0, stream>>>(
      O, WoutF, d_out, boutF, MROWS, 1536, CC, flag);
}

// Round 4
// 1555.495 us; speedup vs baseline: 8.6852x; 8.6852x over previous
//
#include <hip/hip_runtime.h>
#include <hip/hip_bf16.h>
#include <math.h>

// Problem constants
#define BB 4
#define TT 1536
#define CC 1536
#define HH 8
#define DKk 64
#define DVv 192
#define NBASIS 32
#define LREL 3071          // 2T-1
#define MROWS 6144         // B*T

typedef short short8 __attribute__((ext_vector_type(8)));
typedef float floatx4 __attribute__((ext_vector_type(4)));

static __device__ inline short f2bf(float f) {
  __hip_bfloat16 h = __float2bfloat16(f);
  return *reinterpret_cast<short*>(&h);
}

// ---------------------------------------------------------------------------
// Stage 0: dtype detection (fp32 vs bf16 input payloads). See round-1 notes.
// ---------------------------------------------------------------------------
__global__ void detect_kernel(const void* __restrict__ x, int* __restrict__ flag) {
  if (threadIdx.x == 0 && blockIdx.x == 0) {
    const __hip_bfloat16* h = (const __hip_bfloat16*)x;
    int cnt = 0;
    for (int i = 0; i < 64; ++i) {
      float v = fabsf((float)h[2 * i]);
      if (v > 1e-5f && v < 256.0f) cnt++;
    }
    *flag = (cnt >= 32) ? 1 : 0;  // 1 => inputs are bf16
  }
}

__global__ __launch_bounds__(256) void convert_kernel(const void* __restrict__ src,
                                                      float* __restrict__ dst, int n,
                                                      const int* __restrict__ flag) {
  const int i = blockIdx.x * 256 + threadIdx.x;
  if (i >= n) return;
  if (*flag) dst[i] = (float)((const __hip_bfloat16*)src)[i];
  else       dst[i] = ((const float*)src)[i];
}

// ---------------------------------------------------------------------------
// Stage 1: gamma-basis max over pos (fp64). One block per basis j.
// ---------------------------------------------------------------------------
__global__ void gmax_kernel(double* __restrict__ gmax) {
  const int j = blockIdx.x;
  const double mean = 48.0 + 1488.0 * (double)j / 31.0;
  const double conc = (mean / 24.0) * (mean / 24.0);
  const double rate = mean / 576.0;
  const double log_norm = lgamma(conc) - conc * log(rate);
  double mx = 1e-8;
  for (int pos = 1 + threadIdx.x; pos <= 1535; pos += 256) {
    double p = exp((conc - 1.0) * log((double)pos) - rate * (double)pos - log_norm) + 1e-8;
    mx = fmax(mx, p);
  }
  __shared__ double red[256];
  red[threadIdx.x] = mx;
  __syncthreads();
  for (int s = 128; s > 0; s >>= 1) {
    if (threadIdx.x < s) red[threadIdx.x] = fmax(red[threadIdx.x], red[threadIdx.x + s]);
    __syncthreads();
  }
  if (threadIdx.x == 0) gmax[j] = red[0];
}

// ---------------------------------------------------------------------------
// Stage 2: pe[l, f], fp64 math, fp32 store.
// ---------------------------------------------------------------------------
__global__ void pe_kernel(float* __restrict__ pe, const double* __restrict__ gmax) {
  const int l = blockIdx.x;
  const int f = threadIdx.x;  // 0..191
  const int dist = l - (TT - 1);
  const int pos = dist < 0 ? -dist : dist;
  const int base = f % 96;
  const int cls = base / 32;
  const int j = base % 32;
  double v;
  if (cls == 0) {
    const double max_range = log(1536.0) / log(2.0);
    const double e = 3.0 + (max_range - 3.0) * (double)j / 31.0;
    const double hl = exp2(e);
    v = exp2(-(double)pos / hl);
  } else if (cls == 1) {
    const double width = exp2((double)(j + 1)) - 1.0;
    v = (width > (double)pos) ? 1.0 : 0.0;
  } else {
    const double mean = 48.0 + 1488.0 * (double)j / 31.0;
    const double conc = (mean / 24.0) * (mean / 24.0);
    const double rate = mean / 576.0;
    double p;
    if (pos == 0) {
      p = 1e-8;
    } else {
      const double log_norm = lgamma(conc) - conc * log(rate);
      p = exp((conc - 1.0) * log((double)pos) - rate * (double)pos - log_norm) + 1e-8;
    }
    v = p / gmax[j];
  }
  float out = (float)v;
  if (f >= 96) {
    float sgn = (dist > 0) ? 1.f : (dist < 0 ? -1.f : 0.f);
    out *= sgn;
  }
  pe[(size_t)l * 192 + f] = out;
}

// ---------------------------------------------------------------------------
// Stage 3: rKl[h][l][d] (bf16) = sum_f pe[l,f] * W_rel_k[f, h*64+d]
// ---------------------------------------------------------------------------
__global__ __launch_bounds__(512) void relk_kernel(const float* __restrict__ pe,
                                                   const float* __restrict__ Wrk,
                                                   __hip_bfloat16* __restrict__ rKl) {
  __shared__ float pes[8][192];
  const int l0 = blockIdx.x * 8;
  const int nrows = (LREL - l0) < 8 ? (LREL - l0) : 8;
  const int tid = threadIdx.x;
  for (int idx = tid; idx < nrows * 192; idx += 512) {
    int r = idx / 192, f = idx % 192;
    pes[r][f] = pe[(size_t)(l0 + r) * 192 + f];
  }
  __syncthreads();
  float acc[8] = {0.f, 0.f, 0.f, 0.f, 0.f, 0.f, 0.f, 0.f};
  for (int f = 0; f < 192; ++f) {
    float w = Wrk[(size_t)f * 512 + tid];
#pragma unroll
    for (int r = 0; r < 8; ++r) acc[r] += pes[r][f] * w;
  }
  const int h = tid >> 6, d = tid & 63;
  for (int r = 0; r < nrows; ++r)
    rKl[((size_t)h * LREL + (l0 + r)) * 64 + d] = __float2bfloat16(acc[r]);
}

// ---------------------------------------------------------------------------
// Tiled fp32 GEMM. MODE 0: fp32 out; 1: bf16 out; 2: d_out per flag.
// ---------------------------------------------------------------------------
template <int MODE, bool BIAS>
__global__ __launch_bounds__(256) void gemm64(const float* __restrict__ A,
                                              const float* __restrict__ B,
                                              void* __restrict__ Cout,
                                              const float* __restrict__ bias,
                                              int M, int N, int K,
                                              const int* __restrict__ flag) {
  __shared__ float As[64][17];
  __shared__ float Bs[16][68];
  const int tid = threadIdx.x;
  const int tx = tid & 15, ty = tid >> 4;
  const int row0 = blockIdx.y * 64, col0 = blockIdx.x * 64;
  float acc[4][4] = {};
  for (int k0 = 0; k0 < K; k0 += 16) {
    {
      const int ar = tid >> 2, ac = (tid & 3) * 4;
      const float* ap = A + (size_t)(row0 + ar) * K + (k0 + ac);
#pragma unroll
      for (int i = 0; i < 4; ++i) As[ar][ac + i] = ap[i];
      const int bc = tid & 63, br4 = (tid >> 6) * 4;
#pragma unroll
      for (int i = 0; i < 4; ++i)
        Bs[br4 + i][bc] = B[(size_t)(k0 + br4 + i) * N + (col0 + bc)];
    }
    __syncthreads();
#pragma unroll
    for (int kk = 0; kk < 16; ++kk) {
      float a[4], b[4];
#pragma unroll
      for (int i = 0; i < 4; ++i) a[i] = As[ty * 4 + i][kk];
#pragma unroll
      for (int j = 0; j < 4; ++j) b[j] = Bs[kk][tx * 4 + j];
#pragma unroll
      for (int i = 0; i < 4; ++i)
#pragma unroll
        for (int j = 0; j < 4; ++j) acc[i][j] += a[i] * b[j];
    }
    __syncthreads();
  }
  const bool obf = (MODE == 2) ? (*flag != 0) : false;
#pragma unroll
  for (int i = 0; i < 4; ++i) {
    const int r = row0 + ty * 4 + i;
#pragma unroll
    for (int j = 0; j < 4; ++j) {
      const int c = col0 + tx * 4 + j;
      float v = acc[i][j];
      if (BIAS) v += bias[c];
      if (MODE == 0) {
        ((float*)Cout)[(size_t)r * N + c] = v;
      } else if (MODE == 1) {
        ((__hip_bfloat16*)Cout)[(size_t)r * N + c] = __float2bfloat16(v);
      } else {
        if (obf) ((__hip_bfloat16*)Cout)[(size_t)r * N + c] = __float2bfloat16(v);
        else     ((float*)Cout)[(size_t)r * N + c] = v;
      }
    }
  }
}

// ---------------------------------------------------------------------------
// V transpose: V fp32 [b, t, h*192+v]  ->  Vtg bf16 [(b*8+h)*192 + v][1536 t]
// ---------------------------------------------------------------------------
__global__ __launch_bounds__(256) void vtrans_kernel(const float* __restrict__ V,
                                                     __hip_bfloat16* __restrict__ Vtg) {
  int bid = blockIdx.x;            // 4*8*24*3 = 2304
  int vt = bid % 3; int tt = (bid / 3) % 24; int h = (bid / 72) & 7; int b = bid / 576;
  __shared__ __hip_bfloat16 tile[64][72];
  const int tid = threadIdx.x;
  {
    int r = tid >> 2, c0 = (tid & 3) * 16;   // r: t-row, c: v-col
    const float* src = V + (size_t)(b * TT + tt * 64 + r) * 1536 + h * 192 + vt * 64 + c0;
#pragma unroll
    for (int u = 0; u < 16; ++u) tile[r][c0 + u] = __float2bfloat16(src[u]);
  }
  __syncthreads();
  {
    int vr = tid >> 2, t0 = (tid & 3) * 16;
    __hip_bfloat16* dst = Vtg + ((size_t)((b * 8 + h) * 192) + vt * 64 + vr) * 1536 + tt * 64 + t0;
    union { uint4 u4[2]; unsigned short us[16]; } pk;
#pragma unroll
    for (int u = 0; u < 16; ++u) pk.us[u] = *(const unsigned short*)&tile[t0 + u][vr];
    *(uint4*)(dst) = pk.u4[0];
    *(uint4*)(dst + 8) = pk.u4[1];
  }
}

// ---------------------------------------------------------------------------
// MFMA flash attention. Block = (b, h, 64-row q tile); 4 waves, 256 thr.
// S = Qw.K^T (content) + shift-gathered Qr.rK^T (rel window GEMM).
// ---------------------------------------------------------------------------
__global__ __launch_bounds__(256, 3) void attn_mfma(
    const float* __restrict__ tmpQ,                 // [b*T+t][512] fp32
    const float* __restrict__ rwb,                  // [512]
    const float* __restrict__ rrb,                  // [512]
    const __hip_bfloat16* __restrict__ Kbf,         // [b*T+t][512] bf16
    const __hip_bfloat16* __restrict__ rKl,         // [h*3071+l][64] bf16
    const __hip_bfloat16* __restrict__ Vtg,         // [(b*8+h)*192+v][1536] bf16
    float* __restrict__ O)                          // [b*T+q][1536] fp32
{
  const int tid = threadIdx.x;
  const int w = tid >> 6, lane = tid & 63;
  const int quad = lane >> 4, l16 = lane & 15;
  const int bid = blockIdx.x;
  const int qt = bid % 24;
  const int h = (bid / 24) & 7;
  const int b = bid / 192;
  const int q0 = qt * 64;

  // LDS regions (bytes): A @0: Ktile[64][72] (9216) + rKwin[128][72] (18432) = 27648
  //   Rbuf[64][132] bf16 (16896) aliases rKwin after B3 ; Ptile[64][72] aliases Ktile
  // B @27648: Vtile[96][72] bf16 (13824).  Total 41472 -> 3 blocks/CU.
  __shared__ __align__(16) char sm[41472];
  __hip_bfloat16* Ktile = (__hip_bfloat16*)sm;
  __hip_bfloat16* rKwin = (__hip_bfloat16*)(sm + 9216);
  __hip_bfloat16* Rbuf  = (__hip_bfloat16*)(sm + 9216);
  __hip_bfloat16* Ptile = (__hip_bfloat16*)sm;
  __hip_bfloat16* Vtile = (__hip_bfloat16*)(sm + 27648);

  // Q fragments (A-layout): lane holds A[m=l16][k=quad*8+j], kstep*32 offset.
  short8 aQw[2], aQr[2];
  {
    const int qrow = q0 + w * 16 + l16;
    const float* qp = tmpQ + (size_t)(b * TT + qrow) * 512 + h * 64;
#pragma unroll
    for (int ks = 0; ks < 2; ++ks) {
#pragma unroll
      for (int j = 0; j < 8; ++j) {
        const int d = ks * 32 + quad * 8 + j;
        const float qv = qp[d] * 0.125f;
        aQw[ks][j] = f2bf(qv + rwb[h * 64 + d]);
        aQr[ks][j] = f2bf(qv + rrb[h * 64 + d]);
      }
    }
  }

  const floatx4 vzero = {0.f, 0.f, 0.f, 0.f};
  floatx4 Oacc[12];
#pragma unroll
  for (int i = 0; i < 12; ++i) Oacc[i] = vzero;
  float mrow[4], lrow[4];
#pragma unroll
  for (int r = 0; r < 4; ++r) { mrow[r] = -INFINITY; lrow[r] = 0.f; }

  const size_t kBase = (size_t)(b * TT) * 512 + h * 64;
  const __hip_bfloat16* VtgB = Vtg + ((size_t)(b * 8 + h) * 192) * 1536;
  const int l0base = 1472 - q0;   // l0 = k0 + l0base; window rows j=0..127

  for (int k0 = 0; k0 < TT; k0 += 64) {
    __syncthreads();  // B1: prev-iter P/Vtile reads done
    {   // stage Ktile (64 x 64): 4 threads/row, 16 bf16 each
      const int r = tid >> 2, c0 = (tid & 3) * 16;
      const __hip_bfloat16* src = Kbf + kBase + (size_t)(k0 + r) * 512 + c0;
      *(uint4*)(Ktile + r * 72 + c0)     = *(const uint4*)(src);
      *(uint4*)(Ktile + r * 72 + c0 + 8) = *(const uint4*)(src + 8);
    }
    {   // stage rKwin (128 x 64): 2 threads/row, 32 bf16 each
      const int r = tid >> 1, c0 = (tid & 1) * 32;
      int l = l0base + k0 + r;
      l = l < 3070 ? l : 3070;   // row 127 of last window unused; clamp
      const __hip_bfloat16* src = rKl + ((size_t)h * LREL + l) * 64 + c0;
#pragma unroll
      for (int u = 0; u < 4; ++u)
        *(uint4*)(rKwin + r * 72 + c0 + u * 8) = *(const uint4*)(src + u * 8);
    }
    {   // stage Vtile half0 (v 0..95): 96 rows x 8 chunks x 8 bf16 = full 64 cols
      for (int i = tid; i < 96 * 8; i += 256) {
        const int r = i >> 3, c0 = (i & 7) * 8;
        *(uint4*)(Vtile + r * 72 + c0) =
            *(const uint4*)(VtgB + (size_t)r * 1536 + k0 + c0);
      }
    }
    __syncthreads();  // B2: tiles visible

    floatx4 S[4], R[8];
#pragma unroll
    for (int i = 0; i < 4; ++i) S[i] = vzero;
#pragma unroll
    for (int i = 0; i < 8; ++i) R[i] = vzero;
#pragma unroll
    for (int kt = 0; kt < 4; ++kt) {
#pragma unroll
      for (int ks = 0; ks < 2; ++ks) {
        short8 bK = *(const short8*)(Ktile + (kt * 16 + l16) * 72 + ks * 32 + quad * 8);
        S[kt] = __builtin_amdgcn_mfma_f32_16x16x32_bf16(aQw[ks], bK, S[kt], 0, 0, 0);
      }
    }
#pragma unroll
    for (int jt = 0; jt < 8; ++jt) {
#pragma unroll
      for (int ks = 0; ks < 2; ++ks) {
        short8 bR = *(const short8*)(rKwin + (jt * 16 + l16) * 72 + ks * 32 + quad * 8);
        R[jt] = __builtin_amdgcn_mfma_f32_16x16x32_bf16(aQr[ks], bR, R[jt], 0, 0, 0);
      }
    }
    __syncthreads();  // B3: all K/rK reads done; Rbuf/Ptile writes may begin

    // write R (wave-private rows), then gather the diagonal shift
    // (intra-wave LDS write->read: DS ops from one wave are processed in order)
#pragma unroll
    for (int jt = 0; jt < 8; ++jt) {
#pragma unroll
      for (int r = 0; r < 4; ++r) {
        const int row = w * 16 + quad * 4 + r;
        Rbuf[row * 132 + jt * 16 + l16] = __float2bfloat16(R[jt][r]);
      }
    }
#pragma unroll
    for (int kt = 0; kt < 4; ++kt) {
#pragma unroll
      for (int r = 0; r < 4; ++r) {
        const int row = w * 16 + quad * 4 + r;
        const int j = kt * 16 + l16 + 63 - row;   // in [0,126]
        S[kt][r] += (float)Rbuf[row * 132 + j];
      }
    }

    // online softmax (rows are wave-private; 16 lanes share a row)
    float alpha[4];
#pragma unroll
    for (int r = 0; r < 4; ++r) {
      float mx = fmaxf(fmaxf(S[0][r], S[1][r]), fmaxf(S[2][r], S[3][r]));
#pragma unroll
      for (int off = 8; off > 0; off >>= 1) mx = fmaxf(mx, __shfl_xor(mx, off));
      const float nm = fmaxf(mrow[r], mx);
      alpha[r] = __expf(mrow[r] - nm);
      mrow[r] = nm;
      float ps = 0.f;
#pragma unroll
      for (int kt = 0; kt < 4; ++kt) {
        const float p = __expf(S[kt][r] - nm);
        S[kt][r] = p;
        ps += p;
      }
#pragma unroll
      for (int off = 8; off > 0; off >>= 1) ps += __shfl_xor(ps, off);
      lrow[r] = lrow[r] * alpha[r] + ps;
    }
    // write P (A-layout source, wave-private rows), rescale O
#pragma unroll
    for (int kt = 0; kt < 4; ++kt) {
#pragma unroll
      for (int r = 0; r < 4; ++r) {
        const int row = w * 16 + quad * 4 + r;
        Ptile[row * 72 + kt * 16 + l16] = __float2bfloat16(S[kt][r]);
      }
    }
#pragma unroll
    for (int vt = 0; vt < 12; ++vt)
#pragma unroll
      for (int r = 0; r < 4; ++r) Oacc[vt][r] *= alpha[r];

    // PV half 0 (v 0..95)
    short8 aP[2];
#pragma unroll
    for (int ks = 0; ks < 2; ++ks)
      aP[ks] = *(const short8*)(Ptile + (w * 16 + l16) * 72 + ks * 32 + quad * 8);
#pragma unroll
    for (int vt = 0; vt < 6; ++vt) {
#pragma unroll
      for (int ks = 0; ks < 2; ++ks) {
        short8 bV = *(const short8*)(Vtile + (vt * 16 + l16) * 72 + ks * 32 + quad * 8);
        Oacc[vt] = __builtin_amdgcn_mfma_f32_16x16x32_bf16(aP[ks], bV, Oacc[vt], 0, 0, 0);
      }
    }
    __syncthreads();  // B4: PV0 reads done; restage Vtile
    {   // stage Vtile half1 (v 96..191): full 64 cols per row
      for (int i = tid; i < 96 * 8; i += 256) {
        const int r = i >> 3, c0 = (i & 7) * 8;
        *(uint4*)(Vtile + r * 72 + c0) =
            *(const uint4*)(VtgB + (size_t)(96 + r) * 1536 + k0 + c0);
      }
    }
    __syncthreads();  // B5
#pragma unroll
    for (int vt = 6; vt < 12; ++vt) {
#pragma unroll
      for (int ks = 0; ks < 2; ++ks) {
        short8 bV = *(const short8*)(Vtile + ((vt - 6) * 16 + l16) * 72 + ks * 32 + quad * 8);
        Oacc[vt] = __builtin_amdgcn_mfma_f32_16x16x32_bf16(aP[ks], bV, Oacc[vt], 0, 0, 0);
      }
    }
  }

  // epilogue: normalize, store fp32
#pragma unroll
  for (int r = 0; r < 4; ++r) {
    const float inv = 1.f / lrow[r];
    const int qrow = q0 + w * 16 + quad * 4 + r;
    float* op = O + (size_t)(b * TT + qrow) * 1536 + h * 192;
#pragma unroll
    for (int vt = 0; vt < 12; ++vt)
      op[vt * 16 + l16] = Oacc[vt][r] * inv;
  }
}

// ---------------------------------------------------------------------------
extern "C" void kernel_launch(void* const* d_in, const int* in_sizes, int n_in,
                              void* d_out, int out_size, void* d_ws, size_t ws_size,
                              hipStream_t stream) {
  const void* x     = d_in[0];
  const void* W_q   = d_in[1];
  const void* W_k   = d_in[2];
  const void* W_v   = d_in[3];
  const void* W_rel = d_in[4];
  const void* W_out = d_in[5];
  const void* b_out = d_in[6];
  const void* r_w_b = d_in[7];
  const void* r_r_b = d_in[8];

  float* ws = (float*)d_ws;
  int*    flag = (int*)d_ws;                     // 16 floats reserved
  double* gmax = (double*)(ws + 16);             // 64 floats
  float* pe    = ws + 16 + 64;
  float* xF    = pe    + (size_t)LREL * 192;
  float* WqF   = xF    + (size_t)MROWS * 1536;
  float* WkF   = WqF   + (size_t)1536 * 512;
  float* WvF   = WkF   + (size_t)1536 * 512;
  float* WrelF = WvF   + (size_t)1536 * 1536;
  float* WoutF = WrelF + (size_t)192 * 512;
  float* boutF = WoutF + (size_t)1536 * 1536;
  float* rwbF  = boutF + 1536;
  float* rrbF  = rwbF + 512;
  float* tmpQ  = rrbF + 512;                         // 6144*512 fp32
  float* Vf    = tmpQ + (size_t)MROWS * 512;         // 6144*1536 fp32
  float* O     = Vf   + (size_t)MROWS * 1536;        // 6144*1536 fp32
  __hip_bfloat16* Kbf = (__hip_bfloat16*)(O + (size_t)MROWS * 1536);   // 6144*512
  __hip_bfloat16* rKl = Kbf + (size_t)MROWS * 512;                     // 8*3071*64
  __hip_bfloat16* Vtg = rKl + (size_t)HH * LREL * 64;                  // 32*192*1536
  char* endp = (char*)(Vtg + (size_t)32 * 192 * 1536);
  if (ws_size < (size_t)(endp - (char*)d_ws)) return;  // ws too small

  detect_kernel<<<1, 64, 0, stream>>>(x, flag);

  auto conv = [&](const void* src, float* dst, int n) {
    convert_kernel<<<(n + 255) / 256, 256, 0, stream>>>(src, dst, n, flag);
  };
  conv(x,     xF,    MROWS * 1536);
  conv(W_q,   WqF,   1536 * 512);
  conv(W_k,   WkF,   1536 * 512);
  conv(W_v,   WvF,   1536 * 1536);
  conv(W_rel, WrelF, 192 * 512);
  conv(W_out, WoutF, 1536 * 1536);
  conv(b_out, boutF, 1536);
  conv(r_w_b, rwbF,  512);
  conv(r_r_b, rrbF,  512);

  gmax_kernel<<<32, 256, 0, stream>>>(gmax);
  pe_kernel<<<LREL, 192, 0, stream>>>(pe, gmax);
  relk_kernel<<<(LREL + 7) / 8, 512, 0, stream>>>(pe, WrelF, rKl);

  gemm64<0, false><<<dim3(8, 96), 256, 0, stream>>>(
      xF, WqF, tmpQ, nullptr, MROWS, 512, CC, flag);
  gemm64<1, false><<<dim3(8, 96), 256, 0, stream>>>(
      xF, WkF, Kbf, nullptr, MROWS, 512, CC, flag);
  gemm64<0, false><<<dim3(24, 96), 256, 0, stream>>>(
      xF, WvF, Vf, nullptr, MROWS, 1536, CC, flag);

  vtrans_kernel<<<2304, 256, 0, stream>>>(Vf, Vtg);

  attn_mfma<<<768, 256, 0, stream>>>(tmpQ, rwbF, rrbF, Kbf, rKl, Vtg, O);

  gemm64<2, true><<<dim3(24, 96), 256, 0, stream>>>(
      O, WoutF, d_out, boutF, MROWS, 1536, CC, flag);
}

// Round 5
// 547.050 us; speedup vs baseline: 24.6956x; 2.8434x over previous
//
#include <hip/hip_runtime.h>
#include <hip/hip_bf16.h>
#include <math.h>

// Problem constants
#define BB 4
#define TT 1536
#define CC 1536
#define HH 8
#define DKk 64
#define DVv 192
#define NBASIS 32
#define LREL 3071          // 2T-1
#define MROWS 6144         // B*T

typedef short short8 __attribute__((ext_vector_type(8)));
typedef float floatx4 __attribute__((ext_vector_type(4)));

static __device__ inline short f2bf(float f) {
  __hip_bfloat16 h = __float2bfloat16(f);
  return *reinterpret_cast<short*>(&h);
}

// async global->LDS, 16B per lane; LDS dest = wave-uniform base + lane*16
static __device__ inline void gload_lds16(const __hip_bfloat16* g, __hip_bfloat16* l) {
  __builtin_amdgcn_global_load_lds(
      (const __attribute__((address_space(1))) unsigned int*)g,
      (__attribute__((address_space(3))) unsigned int*)l, 16, 0, 0);
}

// ---------------------------------------------------------------------------
// Stage 0: dtype detection (fp32 vs bf16 input payloads). See round-1 notes.
// ---------------------------------------------------------------------------
__global__ void detect_kernel(const void* __restrict__ x, int* __restrict__ flag) {
  if (threadIdx.x == 0 && blockIdx.x == 0) {
    const __hip_bfloat16* h = (const __hip_bfloat16*)x;
    int cnt = 0;
    for (int i = 0; i < 64; ++i) {
      float v = fabsf((float)h[2 * i]);
      if (v > 1e-5f && v < 256.0f) cnt++;
    }
    *flag = (cnt >= 32) ? 1 : 0;  // 1 => inputs are bf16
  }
}

__global__ __launch_bounds__(256) void convert_kernel(const void* __restrict__ src,
                                                      float* __restrict__ dst, int n,
                                                      const int* __restrict__ flag) {
  const int i = blockIdx.x * 256 + threadIdx.x;
  if (i >= n) return;
  if (*flag) dst[i] = (float)((const __hip_bfloat16*)src)[i];
  else       dst[i] = ((const float*)src)[i];
}

__global__ __launch_bounds__(256) void convbf_kernel(const void* __restrict__ src,
                                                     __hip_bfloat16* __restrict__ dst, int n,
                                                     const int* __restrict__ flag) {
  const int i = blockIdx.x * 256 + threadIdx.x;
  if (i >= n) return;
  if (*flag) dst[i] = ((const __hip_bfloat16*)src)[i];
  else       dst[i] = __float2bfloat16(((const float*)src)[i]);
}

// ---------------------------------------------------------------------------
// Weight transpose: src [K,N] (fp32/bf16 per flag) -> dst bf16 [N,K]
// ---------------------------------------------------------------------------
__global__ __launch_bounds__(256) void wt_kernel(const void* __restrict__ src,
                                                 __hip_bfloat16* __restrict__ dst,
                                                 int K, int N, const int* __restrict__ flag) {
  __shared__ __hip_bfloat16 tile[64][68];
  const int tid = threadIdx.x;
  const int k0 = blockIdx.y * 64, n0 = blockIdx.x * 64;
  const bool bf = (*flag != 0);
  {
    const int r = tid >> 2, c0 = (tid & 3) * 16;
    if (bf) {
      const __hip_bfloat16* sp = (const __hip_bfloat16*)src + (size_t)(k0 + r) * N + n0 + c0;
#pragma unroll
      for (int u = 0; u < 16; ++u) tile[r][c0 + u] = sp[u];
    } else {
      const float* sp = (const float*)src + (size_t)(k0 + r) * N + n0 + c0;
#pragma unroll
      for (int u = 0; u < 16; ++u) tile[r][c0 + u] = __float2bfloat16(sp[u]);
    }
  }
  __syncthreads();
  {
    const int nr = tid >> 2, c0 = (tid & 3) * 16;
    __hip_bfloat16* dp = dst + (size_t)(n0 + nr) * K + k0 + c0;
#pragma unroll
    for (int u = 0; u < 16; ++u) dp[u] = tile[c0 + u][nr];
  }
}

// ---------------------------------------------------------------------------
// Stage 1: gamma-basis max over pos (fp64). One block per basis j.
// ---------------------------------------------------------------------------
__global__ void gmax_kernel(double* __restrict__ gmax) {
  const int j = blockIdx.x;
  const double mean = 48.0 + 1488.0 * (double)j / 31.0;
  const double conc = (mean / 24.0) * (mean / 24.0);
  const double rate = mean / 576.0;
  const double log_norm = lgamma(conc) - conc * log(rate);
  double mx = 1e-8;
  for (int pos = 1 + threadIdx.x; pos <= 1535; pos += 256) {
    double p = exp((conc - 1.0) * log((double)pos) - rate * (double)pos - log_norm) + 1e-8;
    mx = fmax(mx, p);
  }
  __shared__ double red[256];
  red[threadIdx.x] = mx;
  __syncthreads();
  for (int s = 128; s > 0; s >>= 1) {
    if (threadIdx.x < s) red[threadIdx.x] = fmax(red[threadIdx.x], red[threadIdx.x + s]);
    __syncthreads();
  }
  if (threadIdx.x == 0) gmax[j] = red[0];
}

// ---------------------------------------------------------------------------
// Stage 2: pe[l, f], fp64 math, fp32 store.
// ---------------------------------------------------------------------------
__global__ void pe_kernel(float* __restrict__ pe, const double* __restrict__ gmax) {
  const int l = blockIdx.x;
  const int f = threadIdx.x;  // 0..191
  const int dist = l - (TT - 1);
  const int pos = dist < 0 ? -dist : dist;
  const int base = f % 96;
  const int cls = base / 32;
  const int j = base % 32;
  double v;
  if (cls == 0) {
    const double max_range = log(1536.0) / log(2.0);
    const double e = 3.0 + (max_range - 3.0) * (double)j / 31.0;
    const double hl = exp2(e);
    v = exp2(-(double)pos / hl);
  } else if (cls == 1) {
    const double width = exp2((double)(j + 1)) - 1.0;
    v = (width > (double)pos) ? 1.0 : 0.0;
  } else {
    const double mean = 48.0 + 1488.0 * (double)j / 31.0;
    const double conc = (mean / 24.0) * (mean / 24.0);
    const double rate = mean / 576.0;
    double p;
    if (pos == 0) {
      p = 1e-8;
    } else {
      const double log_norm = lgamma(conc) - conc * log(rate);
      p = exp((conc - 1.0) * log((double)pos) - rate * (double)pos - log_norm) + 1e-8;
    }
    v = p / gmax[j];
  }
  float out = (float)v;
  if (f >= 96) {
    float sgn = (dist > 0) ? 1.f : (dist < 0 ? -1.f : 0.f);
    out *= sgn;
  }
  pe[(size_t)l * 192 + f] = out;
}

// ---------------------------------------------------------------------------
// Stage 3: rKl[h][l][d] (bf16) = sum_f pe[l,f] * W_rel_k[f, h*64+d]
// ---------------------------------------------------------------------------
__global__ __launch_bounds__(512) void relk_kernel(const float* __restrict__ pe,
                                                   const float* __restrict__ Wrk,
                                                   __hip_bfloat16* __restrict__ rKl) {
  __shared__ float pes[8][192];
  const int l0 = blockIdx.x * 8;
  const int nrows = (LREL - l0) < 8 ? (LREL - l0) : 8;
  const int tid = threadIdx.x;
  for (int idx = tid; idx < nrows * 192; idx += 512) {
    int r = idx / 192, f = idx % 192;
    pes[r][f] = pe[(size_t)(l0 + r) * 192 + f];
  }
  __syncthreads();
  float acc[8] = {0.f, 0.f, 0.f, 0.f, 0.f, 0.f, 0.f, 0.f};
  for (int f = 0; f < 192; ++f) {
    float w = Wrk[(size_t)f * 512 + tid];
#pragma unroll
    for (int r = 0; r < 8; ++r) acc[r] += pes[r][f] * w;
  }
  const int h = tid >> 6, d = tid & 63;
  for (int r = 0; r < nrows; ++r)
    rKl[((size_t)h * LREL + (l0 + r)) * 64 + d] = __float2bfloat16(acc[r]);
}

// ---------------------------------------------------------------------------
// bf16 MFMA GEMM (m97 structure): C[M,N] = A[M,K] @ Bt[N,K]^T
// 128x128 tile, BK=32, 4 waves, global_load_lds staging, ds_read_b128 frags.
// MODE 0: fp32 out; 1: bf16 out; 2: d_out per flag (+bias).
// ---------------------------------------------------------------------------
template <int MODE, bool BIAS>
__global__ __launch_bounds__(256) void gemm_mfma(const __hip_bfloat16* __restrict__ A,
                                                 const __hip_bfloat16* __restrict__ Bt,
                                                 void* __restrict__ Cout,
                                                 const float* __restrict__ bias,
                                                 int M, int N, int K,
                                                 const int* __restrict__ flag) {
  __shared__ __align__(16) __hip_bfloat16 As[128 * 32];
  __shared__ __align__(16) __hip_bfloat16 Bs[128 * 32];
  const int tid = threadIdx.x;
  const int w = tid >> 6, lane = tid & 63;
  const int quad = lane >> 4, l16 = lane & 15;
  const int wm = w >> 1, wn = w & 1;
  const int row0 = blockIdx.y * 128, col0 = blockIdx.x * 128;

  const floatx4 vzero = {0.f, 0.f, 0.f, 0.f};
  floatx4 acc[4][4];
#pragma unroll
  for (int i = 0; i < 4; ++i)
#pragma unroll
    for (int j = 0; j < 4; ++j) acc[i][j] = vzero;

  // staging: wave w covers A rows [w*32, w*32+32) and Bt rows [w*32, w*32+32)
  const int sr = lane >> 2;            // 0..15
  const int sc = (lane & 3) * 8;       // bf16 elems
  const __hip_bfloat16* ag0 = A + (size_t)(row0 + w * 32 + sr) * K + sc;
  const __hip_bfloat16* ag1 = A + (size_t)(row0 + w * 32 + 16 + sr) * K + sc;
  const __hip_bfloat16* bg0 = Bt + (size_t)(col0 + w * 32 + sr) * K + sc;
  const __hip_bfloat16* bg1 = Bt + (size_t)(col0 + w * 32 + 16 + sr) * K + sc;
  __hip_bfloat16* as0 = As + w * 32 * 32;
  __hip_bfloat16* as1 = As + (w * 32 + 16) * 32;
  __hip_bfloat16* bs0 = Bs + w * 32 * 32;
  __hip_bfloat16* bs1 = Bs + (w * 32 + 16) * 32;

  for (int k0 = 0; k0 < K; k0 += 32) {
    __syncthreads();   // prev-iter frag reads done
    gload_lds16(ag0 + k0, as0);
    gload_lds16(ag1 + k0, as1);
    gload_lds16(bg0 + k0, bs0);
    gload_lds16(bg1 + k0, bs1);
    __syncthreads();   // staging visible (vmcnt drained by barrier semantics)
    short8 aF[4], bF[4];
#pragma unroll
    for (int mt = 0; mt < 4; ++mt)
      aF[mt] = *(const short8*)(As + (wm * 64 + mt * 16 + l16) * 32 + quad * 8);
#pragma unroll
    for (int nt = 0; nt < 4; ++nt)
      bF[nt] = *(const short8*)(Bs + (wn * 64 + nt * 16 + l16) * 32 + quad * 8);
#pragma unroll
    for (int mt = 0; mt < 4; ++mt)
#pragma unroll
      for (int nt = 0; nt < 4; ++nt)
        acc[mt][nt] = __builtin_amdgcn_mfma_f32_16x16x32_bf16(aF[mt], bF[nt], acc[mt][nt], 0, 0, 0);
  }

  const bool obf = (MODE == 2) ? (*flag != 0) : false;
#pragma unroll
  for (int mt = 0; mt < 4; ++mt) {
#pragma unroll
    for (int r = 0; r < 4; ++r) {
      const int row = row0 + wm * 64 + mt * 16 + quad * 4 + r;
#pragma unroll
      for (int nt = 0; nt < 4; ++nt) {
        const int col = col0 + wn * 64 + nt * 16 + l16;
        float v = acc[mt][nt][r];
        if (BIAS) v += bias[col];
        if (MODE == 0) {
          ((float*)Cout)[(size_t)row * N + col] = v;
        } else if (MODE == 1) {
          ((__hip_bfloat16*)Cout)[(size_t)row * N + col] = __float2bfloat16(v);
        } else {
          if (obf) ((__hip_bfloat16*)Cout)[(size_t)row * N + col] = __float2bfloat16(v);
          else     ((float*)Cout)[(size_t)row * N + col] = v;
        }
      }
    }
  }
}

// ---------------------------------------------------------------------------
// V transpose: Vbf bf16 [b*T+t][h*192+v] -> Vtg bf16 [(b*8+h)*192 + v][1536 t]
// ---------------------------------------------------------------------------
__global__ __launch_bounds__(256) void vtrans_kernel(const __hip_bfloat16* __restrict__ Vbf,
                                                     __hip_bfloat16* __restrict__ Vtg) {
  int bid = blockIdx.x;            // 4*8*24*3 = 2304
  int vt = bid % 3; int tt = (bid / 3) % 24; int h = (bid / 72) & 7; int b = bid / 576;
  __shared__ __hip_bfloat16 tile[64][72];
  const int tid = threadIdx.x;
  {
    int r = tid >> 2, c0 = (tid & 3) * 16;   // r: t-row, c: v-col
    const __hip_bfloat16* src = Vbf + (size_t)(b * TT + tt * 64 + r) * 1536 + h * 192 + vt * 64 + c0;
#pragma unroll
    for (int u = 0; u < 16; ++u) tile[r][c0 + u] = src[u];
  }
  __syncthreads();
  {
    int vr = tid >> 2, t0 = (tid & 3) * 16;
    __hip_bfloat16* dst = Vtg + ((size_t)((b * 8 + h) * 192) + vt * 64 + vr) * 1536 + tt * 64 + t0;
    union { uint4 u4[2]; unsigned short us[16]; } pk;
#pragma unroll
    for (int u = 0; u < 16; ++u) pk.us[u] = *(const unsigned short*)&tile[t0 + u][vr];
    *(uint4*)(dst) = pk.u4[0];
    *(uint4*)(dst + 8) = pk.u4[1];
  }
}

// ---------------------------------------------------------------------------
// MFMA flash attention. Block = (b, h, 64-row q tile); 4 waves, 256 thr.
// ---------------------------------------------------------------------------
__global__ __launch_bounds__(256, 3) void attn_mfma(
    const float* __restrict__ tmpQ,                 // [b*T+t][512] fp32
    const float* __restrict__ rwb,                  // [512]
    const float* __restrict__ rrb,                  // [512]
    const __hip_bfloat16* __restrict__ Kbf,         // [b*T+t][512] bf16
    const __hip_bfloat16* __restrict__ rKl,         // [h*3071+l][64] bf16
    const __hip_bfloat16* __restrict__ Vtg,         // [(b*8+h)*192+v][1536] bf16
    __hip_bfloat16* __restrict__ O)                 // [b*T+q][1536] bf16
{
  const int tid = threadIdx.x;
  const int w = tid >> 6, lane = tid & 63;
  const int quad = lane >> 4, l16 = lane & 15;
  const int bid = blockIdx.x;
  const int qt = bid % 24;
  const int h = (bid / 24) & 7;
  const int b = bid / 192;
  const int q0 = qt * 64;

  __shared__ __align__(16) char sm[41472];
  __hip_bfloat16* Ktile = (__hip_bfloat16*)sm;
  __hip_bfloat16* rKwin = (__hip_bfloat16*)(sm + 9216);
  __hip_bfloat16* Rbuf  = (__hip_bfloat16*)(sm + 9216);
  __hip_bfloat16* Ptile = (__hip_bfloat16*)sm;
  __hip_bfloat16* Vtile = (__hip_bfloat16*)(sm + 27648);

  short8 aQw[2], aQr[2];
  {
    const int qrow = q0 + w * 16 + l16;
    const float* qp = tmpQ + (size_t)(b * TT + qrow) * 512 + h * 64;
#pragma unroll
    for (int ks = 0; ks < 2; ++ks) {
#pragma unroll
      for (int j = 0; j < 8; ++j) {
        const int d = ks * 32 + quad * 8 + j;
        const float qv = qp[d] * 0.125f;
        aQw[ks][j] = f2bf(qv + rwb[h * 64 + d]);
        aQr[ks][j] = f2bf(qv + rrb[h * 64 + d]);
      }
    }
  }

  const floatx4 vzero = {0.f, 0.f, 0.f, 0.f};
  floatx4 Oacc[12];
#pragma unroll
  for (int i = 0; i < 12; ++i) Oacc[i] = vzero;
  float mrow[4], lrow[4];
#pragma unroll
  for (int r = 0; r < 4; ++r) { mrow[r] = -INFINITY; lrow[r] = 0.f; }

  const size_t kBase = (size_t)(b * TT) * 512 + h * 64;
  const __hip_bfloat16* VtgB = Vtg + ((size_t)(b * 8 + h) * 192) * 1536;
  const int l0base = 1472 - q0;

  for (int k0 = 0; k0 < TT; k0 += 64) {
    __syncthreads();  // B1
    {
      const int r = tid >> 2, c0 = (tid & 3) * 16;
      const __hip_bfloat16* src = Kbf + kBase + (size_t)(k0 + r) * 512 + c0;
      *(uint4*)(Ktile + r * 72 + c0)     = *(const uint4*)(src);
      *(uint4*)(Ktile + r * 72 + c0 + 8) = *(const uint4*)(src + 8);
    }
    {
      const int r = tid >> 1, c0 = (tid & 1) * 32;
      int l = l0base + k0 + r;
      l = l < 3070 ? l : 3070;
      const __hip_bfloat16* src = rKl + ((size_t)h * LREL + l) * 64 + c0;
#pragma unroll
      for (int u = 0; u < 4; ++u)
        *(uint4*)(rKwin + r * 72 + c0 + u * 8) = *(const uint4*)(src + u * 8);
    }
    {
      for (int i = tid; i < 96 * 8; i += 256) {
        const int r = i >> 3, c0 = (i & 7) * 8;
        *(uint4*)(Vtile + r * 72 + c0) =
            *(const uint4*)(VtgB + (size_t)r * 1536 + k0 + c0);
      }
    }
    __syncthreads();  // B2

    floatx4 S[4], R[8];
#pragma unroll
    for (int i = 0; i < 4; ++i) S[i] = vzero;
#pragma unroll
    for (int i = 0; i < 8; ++i) R[i] = vzero;
#pragma unroll
    for (int kt = 0; kt < 4; ++kt) {
#pragma unroll
      for (int ks = 0; ks < 2; ++ks) {
        short8 bK = *(const short8*)(Ktile + (kt * 16 + l16) * 72 + ks * 32 + quad * 8);
        S[kt] = __builtin_amdgcn_mfma_f32_16x16x32_bf16(aQw[ks], bK, S[kt], 0, 0, 0);
      }
    }
#pragma unroll
    for (int jt = 0; jt < 8; ++jt) {
#pragma unroll
      for (int ks = 0; ks < 2; ++ks) {
        short8 bR = *(const short8*)(rKwin + (jt * 16 + l16) * 72 + ks * 32 + quad * 8);
        R[jt] = __builtin_amdgcn_mfma_f32_16x16x32_bf16(aQr[ks], bR, R[jt], 0, 0, 0);
      }
    }
    __syncthreads();  // B3

#pragma unroll
    for (int jt = 0; jt < 8; ++jt) {
#pragma unroll
      for (int r = 0; r < 4; ++r) {
        const int row = w * 16 + quad * 4 + r;
        Rbuf[row * 132 + jt * 16 + l16] = __float2bfloat16(R[jt][r]);
      }
    }
#pragma unroll
    for (int kt = 0; kt < 4; ++kt) {
#pragma unroll
      for (int r = 0; r < 4; ++r) {
        const int row = w * 16 + quad * 4 + r;
        const int j = kt * 16 + l16 + 63 - row;   // in [0,126]
        S[kt][r] += (float)Rbuf[row * 132 + j];
      }
    }

    float alpha[4];
#pragma unroll
    for (int r = 0; r < 4; ++r) {
      float mx = fmaxf(fmaxf(S[0][r], S[1][r]), fmaxf(S[2][r], S[3][r]));
#pragma unroll
      for (int off = 8; off > 0; off >>= 1) mx = fmaxf(mx, __shfl_xor(mx, off));
      const float nm = fmaxf(mrow[r], mx);
      alpha[r] = __expf(mrow[r] - nm);
      mrow[r] = nm;
      float ps = 0.f;
#pragma unroll
      for (int kt = 0; kt < 4; ++kt) {
        const float p = __expf(S[kt][r] - nm);
        S[kt][r] = p;
        ps += p;
      }
#pragma unroll
      for (int off = 8; off > 0; off >>= 1) ps += __shfl_xor(ps, off);
      lrow[r] = lrow[r] * alpha[r] + ps;
    }
#pragma unroll
    for (int kt = 0; kt < 4; ++kt) {
#pragma unroll
      for (int r = 0; r < 4; ++r) {
        const int row = w * 16 + quad * 4 + r;
        Ptile[row * 72 + kt * 16 + l16] = __float2bfloat16(S[kt][r]);
      }
    }
#pragma unroll
    for (int vt = 0; vt < 12; ++vt)
#pragma unroll
      for (int r = 0; r < 4; ++r) Oacc[vt][r] *= alpha[r];

    short8 aP[2];
#pragma unroll
    for (int ks = 0; ks < 2; ++ks)
      aP[ks] = *(const short8*)(Ptile + (w * 16 + l16) * 72 + ks * 32 + quad * 8);
#pragma unroll
    for (int vt = 0; vt < 6; ++vt) {
#pragma unroll
      for (int ks = 0; ks < 2; ++ks) {
        short8 bV = *(const short8*)(Vtile + (vt * 16 + l16) * 72 + ks * 32 + quad * 8);
        Oacc[vt] = __builtin_amdgcn_mfma_f32_16x16x32_bf16(aP[ks], bV, Oacc[vt], 0, 0, 0);
      }
    }
    __syncthreads();  // B4
    {
      for (int i = tid; i < 96 * 8; i += 256) {
        const int r = i >> 3, c0 = (i & 7) * 8;
        *(uint4*)(Vtile + r * 72 + c0) =
            *(const uint4*)(VtgB + (size_t)(96 + r) * 1536 + k0 + c0);
      }
    }
    __syncthreads();  // B5
#pragma unroll
    for (int vt = 6; vt < 12; ++vt) {
#pragma unroll
      for (int ks = 0; ks < 2; ++ks) {
        short8 bV = *(const short8*)(Vtile + ((vt - 6) * 16 + l16) * 72 + ks * 32 + quad * 8);
        Oacc[vt] = __builtin_amdgcn_mfma_f32_16x16x32_bf16(aP[ks], bV, Oacc[vt], 0, 0, 0);
      }
    }
  }

  // epilogue: normalize, store bf16 (feeds MFMA out-projection)
#pragma unroll
  for (int r = 0; r < 4; ++r) {
    const float inv = 1.f / lrow[r];
    const int qrow = q0 + w * 16 + quad * 4 + r;
    __hip_bfloat16* op = O + (size_t)(b * TT + qrow) * 1536 + h * 192;
#pragma unroll
    for (int vt = 0; vt < 12; ++vt)
      op[vt * 16 + l16] = __float2bfloat16(Oacc[vt][r] * inv);
  }
}

// ---------------------------------------------------------------------------
extern "C" void kernel_launch(void* const* d_in, const int* in_sizes, int n_in,
                              void* d_out, int out_size, void* d_ws, size_t ws_size,
                              hipStream_t stream) {
  const void* x     = d_in[0];
  const void* W_q   = d_in[1];
  const void* W_k   = d_in[2];
  const void* W_v   = d_in[3];
  const void* W_rel = d_in[4];
  const void* W_out = d_in[5];
  const void* b_out = d_in[6];
  const void* r_w_b = d_in[7];
  const void* r_r_b = d_in[8];

  float* ws = (float*)d_ws;
  int*    flag = (int*)d_ws;                     // 16 floats reserved
  double* gmax = (double*)(ws + 16);             // 64 floats
  float* pe    = ws + 16 + 64;                   // 3071*192
  float* WrelF = pe    + (size_t)LREL * 192;     // 192*512
  float* boutF = WrelF + (size_t)192 * 512;      // 1536
  float* rwbF  = boutF + 1536;                   // 512
  float* rrbF  = rwbF + 512;                     // 512
  float* tmpQ  = rrbF + 512;                     // 6144*512 fp32
  __hip_bfloat16* xBf  = (__hip_bfloat16*)(tmpQ + (size_t)MROWS * 512);  // 6144*1536
  __hip_bfloat16* WqT  = xBf  + (size_t)MROWS * 1536;     // 512*1536
  __hip_bfloat16* WkT  = WqT  + (size_t)512 * 1536;       // 512*1536
  __hip_bfloat16* WvT  = WkT  + (size_t)512 * 1536;       // 1536*1536
  __hip_bfloat16* WoT  = WvT  + (size_t)1536 * 1536;      // 1536*1536
  __hip_bfloat16* Kbf  = WoT  + (size_t)1536 * 1536;      // 6144*512
  __hip_bfloat16* Vbf  = Kbf  + (size_t)MROWS * 512;      // 6144*1536
  __hip_bfloat16* Vtg  = Vbf  + (size_t)MROWS * 1536;     // 32*192*1536
  __hip_bfloat16* Obf  = Vtg  + (size_t)32 * 192 * 1536;  // 6144*1536
  __hip_bfloat16* rKl  = Obf  + (size_t)MROWS * 1536;     // 8*3071*64
  char* endp = (char*)(rKl + (size_t)HH * LREL * 64);
  if (ws_size < (size_t)(endp - (char*)d_ws)) return;  // ws too small

  detect_kernel<<<1, 64, 0, stream>>>(x, flag);

  auto conv = [&](const void* src, float* dst, int n) {
    convert_kernel<<<(n + 255) / 256, 256, 0, stream>>>(src, dst, n, flag);
  };
  conv(W_rel, WrelF, 192 * 512);
  conv(b_out, boutF, 1536);
  conv(r_w_b, rwbF,  512);
  conv(r_r_b, rrbF,  512);

  convbf_kernel<<<(MROWS * 1536 + 255) / 256, 256, 0, stream>>>(x, xBf, MROWS * 1536, flag);

  // weight transposes: src [K,N] -> dst [N,K] bf16
  wt_kernel<<<dim3(512 / 64, 1536 / 64), 256, 0, stream>>>(W_q, WqT, 1536, 512, flag);
  wt_kernel<<<dim3(512 / 64, 1536 / 64), 256, 0, stream>>>(W_k, WkT, 1536, 512, flag);
  wt_kernel<<<dim3(1536 / 64, 1536 / 64), 256, 0, stream>>>(W_v, WvT, 1536, 1536, flag);
  wt_kernel<<<dim3(1536 / 64, 1536 / 64), 256, 0, stream>>>(W_out, WoT, 1536, 1536, flag);

  gmax_kernel<<<32, 256, 0, stream>>>(gmax);
  pe_kernel<<<LREL, 192, 0, stream>>>(pe, gmax);
  relk_kernel<<<(LREL + 7) / 8, 512, 0, stream>>>(pe, WrelF, rKl);

  // projections (bf16 MFMA)
  gemm_mfma<0, false><<<dim3(512 / 128, MROWS / 128), 256, 0, stream>>>(
      xBf, WqT, tmpQ, nullptr, MROWS, 512, CC, flag);
  gemm_mfma<1, false><<<dim3(512 / 128, MROWS / 128), 256, 0, stream>>>(
      xBf, WkT, Kbf, nullptr, MROWS, 512, CC, flag);
  gemm_mfma<1, false><<<dim3(1536 / 128, MROWS / 128), 256, 0, stream>>>(
      xBf, WvT, Vbf, nullptr, MROWS, 1536, CC, flag);

  vtrans_kernel<<<2304, 256, 0, stream>>>(Vbf, Vtg);

  attn_mfma<<<768, 256, 0, stream>>>(tmpQ, rwbF, rrbF, Kbf, rKl, Vtg, Obf);

  gemm_mfma<2, true><<<dim3(1536 / 128, MROWS / 128), 256, 0, stream>>>(
      Obf, WoT, d_out, boutF, MROWS, 1536, CC, flag);
}